// Round 24
// baseline (336.838 us; speedup 1.0000x reference)
//
#include <hip/hip_runtime.h>

typedef short short8 __attribute__((ext_vector_type(8)));
typedef float f32x4 __attribute__((ext_vector_type(4)));
typedef float f32x16 __attribute__((ext_vector_type(16)));
typedef unsigned short ushort_t;
typedef unsigned int uint_t;

#define HD __device__ __forceinline__
#define NBSHIFT 7   // coarse bucket = 128 combined-dst values

HD ushort_t f2bf(float f) {  // round-to-nearest-even f32 -> bf16 bits
    uint_t u = __float_as_uint(f);
    uint_t r = (u + 0x7fffu + ((u >> 16) & 1u)) >> 16;
    return (ushort_t)r;
}
HD float bf2f(ushort_t h) { return __uint_as_float(((uint_t)h) << 16); }
HD float readlane_f(float v, int l) {
    return __int_as_float(__builtin_amdgcn_readlane(__float_as_int(v), l));
}

// ---------------- MFMA hi/lo split GEMM: C[M,Ntot] = A[M,K] @ B, bf16 output ----------------
__global__ __launch_bounds__(256) void gemm_mfma_hilo_bf16(
    const float* __restrict__ A, const ushort_t* __restrict__ Bth,
    const ushort_t* __restrict__ Btl, ushort_t* __restrict__ C,
    int M, int K, int Ntot) {
    __shared__ ushort_t Ah[128][72], Al[128][72], Bh[128][72], Bl[128][72];
    int tid = threadIdx.x;
    int lane = tid & 63, w = tid >> 6;
    int row0 = blockIdx.x * 128;
    int col0 = blockIdx.y * 128;
    int cl = lane & 31, hi = lane >> 5;
    f32x16 acc[4] = {};
    for (int k0 = 0; k0 < K; k0 += 64) {
        for (int e = tid; e < 4096; e += 256) {
            int r = e >> 5, k2 = e & 31;
            int gr = row0 + r;
            float2 v = {0.f, 0.f};
            if (gr < M) v = *(const float2*)&A[(long)gr * K + k0 + k2 * 2];
            ushort_t h0 = f2bf(v.x); ushort_t l0 = f2bf(v.x - bf2f(h0));
            ushort_t h1 = f2bf(v.y); ushort_t l1 = f2bf(v.y - bf2f(h1));
            *(uint_t*)&Ah[r][k2 * 2] = (uint_t)h0 | ((uint_t)h1 << 16);
            *(uint_t*)&Al[r][k2 * 2] = (uint_t)l0 | ((uint_t)l1 << 16);
        }
        for (int e = tid; e < 4096; e += 256) {
            int n = e >> 5, k2 = e & 31;
            const uint_t* ph = (const uint_t*)&Bth[(long)(col0 + n) * K + k0];
            const uint_t* pl = (const uint_t*)&Btl[(long)(col0 + n) * K + k0];
            *(uint_t*)&Bh[n][k2 * 2] = ph[k2];
            *(uint_t*)&Bl[n][k2 * 2] = pl[k2];
        }
        __syncthreads();
        int arow = w * 32 + cl;
#pragma unroll
        for (int kk = 0; kk < 4; ++kk) {
            int koff = kk * 16 + hi * 8;
            short8 a_h = *(const short8*)&Ah[arow][koff];
            short8 a_l = *(const short8*)&Al[arow][koff];
#pragma unroll
            for (int nf = 0; nf < 4; ++nf) {
                int bcol = nf * 32 + cl;
                short8 b_h = *(const short8*)&Bh[bcol][koff];
                short8 b_l = *(const short8*)&Bl[bcol][koff];
                acc[nf] = __builtin_amdgcn_mfma_f32_32x32x16_bf16(a_h, b_h, acc[nf], 0, 0, 0);
                acc[nf] = __builtin_amdgcn_mfma_f32_32x32x16_bf16(a_l, b_h, acc[nf], 0, 0, 0);
                acc[nf] = __builtin_amdgcn_mfma_f32_32x32x16_bf16(a_h, b_l, acc[nf], 0, 0, 0);
            }
        }
        __syncthreads();
    }
#pragma unroll
    for (int nf = 0; nf < 4; ++nf) {
#pragma unroll
        for (int reg = 0; reg < 16; ++reg) {
            int crow = (reg & 3) + 8 * (reg >> 2) + 4 * hi + w * 32;
            int gr = row0 + crow;
            if (gr < M) C[(long)gr * Ntot + col0 + nf * 32 + cl] = f2bf(acc[nf][reg]);
        }
    }
}

// ---------------- weight prep ----------------
__global__ void prep_bt_conv(const float* __restrict__ Wc, ushort_t* bh, ushort_t* bl) {
    int idx = blockIdx.x * 256 + threadIdx.x;
    if (idx >= 128 * 256) return;
    int n = idx >> 8, k = idx & 255;
    float v = Wc[k * 128 + n];
    ushort_t h = f2bf(v);
    bh[idx] = h;
    bl[idx] = f2bf(v - bf2f(h));
}

// W1 (a,b,c) in half-K MFMA fragment order, bf16-hi:
// idx = m*16384 + h*8192 + (t*2+kk2)*512 + l*8 + e ; kk = 2h+kk2
// col = 16t + (l&15), k = kk*32 + (l>>4)*8 + e
// -> each 16KB half-stage is contiguous; decode ds_read_b128 is wave-contiguous.
__global__ void prep_w1frag2(const float* __restrict__ W1, ushort_t* __restrict__ w1f) {
    int idx = blockIdx.x * 256 + threadIdx.x;
    if (idx >= 3 * 16384) return;
    int m = idx >> 14;
    int rem = idx & 16383;
    int h = rem >> 13;
    int rem2 = rem & 8191;
    int f2 = rem2 >> 9, l = (rem2 >> 3) & 63, e = rem2 & 7;
    int t = f2 >> 1, kk2 = f2 & 1;
    int kk = 2 * h + kk2;
    int col = 16 * t + (l & 15);
    int k = kk * 32 + (l >> 4) * 8 + e;
    w1f[idx] = f2bf(W1[(m * 128 + k) * 128 + col]);
}

// ---------------- CSR build ----------------
__global__ void zero_ints(int* p, int n) {
    int i = blockIdx.x * 256 + threadIdx.x;
    if (i < n) p[i] = 0;
}

__global__ void count_deg(const int* __restrict__ dstI, const int* __restrict__ dstD,
                          int* cnt, int N, int E) {
    int e = blockIdx.x * 256 + threadIdx.x;
    if (e < E) {
        atomicAdd(&cnt[dstI[e]], 1);
        atomicAdd(&cnt[N + dstD[e]], 1);
    }
}

__global__ void scan_partial(const int* __restrict__ cnt, int* partials, int n2) {
    __shared__ int sdata[256];
    int i = blockIdx.x * 256 + threadIdx.x;
    sdata[threadIdx.x] = (i < n2) ? cnt[i] : 0;
    __syncthreads();
    for (int s = 128; s > 0; s >>= 1) {
        if (threadIdx.x < s) sdata[threadIdx.x] += sdata[threadIdx.x + s];
        __syncthreads();
    }
    if (threadIdx.x == 0) partials[blockIdx.x] = sdata[0];
}

__global__ void scan_partials_excl2(int* partials, int nb) {
    __shared__ int sd[512];
    int t = threadIdx.x;
    int v = (t < nb) ? partials[t] : 0;
    sd[t] = v;
    __syncthreads();
    for (int s = 1; s < 512; s <<= 1) {
        int u = (t >= s) ? sd[t - s] : 0;
        __syncthreads();
        sd[t] += u;
        __syncthreads();
    }
    if (t < nb) partials[t] = sd[t] - v;   // exclusive
}

__global__ void scan_final(const int* __restrict__ cnt, const int* __restrict__ partials,
                           int* off, int* cur, float* dI, float* dD, int N, int n2) {
    __shared__ int sdata[256];
    int i = blockIdx.x * 256 + threadIdx.x;
    int v = (i < n2) ? cnt[i] : 0;
    sdata[threadIdx.x] = v;
    __syncthreads();
    for (int s = 1; s < 256; s <<= 1) {
        int t = (threadIdx.x >= s) ? sdata[threadIdx.x - s] : 0;
        __syncthreads();
        sdata[threadIdx.x] += t;
        __syncthreads();
    }
    int excl = sdata[threadIdx.x] - v + partials[blockIdx.x];
    if (i < n2) {
        off[i] = excl; cur[i] = excl;
        float dv = rsqrtf((float)(v + 1));
        if (i < N) dI[i] = dv; else dD[i - N] = dv;
    }
}

// ---- two-level edge sort ----
__global__ __launch_bounds__(256) void coarse_count(
    const int* __restrict__ dstI, const int* __restrict__ dstD,
    int* __restrict__ ccnt, int N, int E, int NB) {
    __shared__ int bins[1024];
    for (int b = threadIdx.x; b < NB; b += 256) bins[b] = 0;
    __syncthreads();
    int stride = gridDim.x * 256;
    for (int e = blockIdx.x * 256 + threadIdx.x; e < E; e += stride) {
        atomicAdd(&bins[dstI[e] >> NBSHIFT], 1);
        atomicAdd(&bins[(N + dstD[e]) >> NBSHIFT], 1);
    }
    __syncthreads();
    for (int b = threadIdx.x; b < NB; b += 256) {
        int v = bins[b];
        if (v) atomicAdd(&ccnt[b], v);
    }
}

__global__ void coarse_scan(const int* __restrict__ ccnt, int* gcur, int NB) {
    __shared__ int sd[1024];
    int t = threadIdx.x;
    int v = (t < NB) ? ccnt[t] : 0;
    sd[t] = v;
    __syncthreads();
    for (int s = 1; s < 1024; s <<= 1) {
        int u = (t >= s) ? sd[t - s] : 0;
        __syncthreads();
        sd[t] += u;
        __syncthreads();
    }
    if (t < NB) gcur[t] = sd[t] - v;
}

// block-aggregated coarse scatter (1 global atomic per block,bucket)
__global__ __launch_bounds__(256) void coarse_scatter2(
    const int* __restrict__ srcI, const int* __restrict__ dstI,
    const int* __restrict__ srcD, const int* __restrict__ dstD,
    int* __restrict__ gcur, int2* __restrict__ tmp, int N, int E, int NB) {
    __shared__ int lcnt[1024];
    __shared__ int lbase[1024];
    int tid = threadIdx.x;
    int chunk = (E + gridDim.x - 1) / gridDim.x;
    int e0 = blockIdx.x * chunk;
    int e1 = min(e0 + chunk, E);
    for (int b = tid; b < NB; b += 256) lcnt[b] = 0;
    __syncthreads();
    for (int e = e0 + tid; e < e1; e += 256) {
        atomicAdd(&lcnt[dstI[e] >> NBSHIFT], 1);
        atomicAdd(&lcnt[(N + dstD[e]) >> NBSHIFT], 1);
    }
    __syncthreads();
    for (int b = tid; b < NB; b += 256) {
        int c = lcnt[b];
        lbase[b] = c ? atomicAdd(&gcur[b], c) : 0;
        lcnt[b] = 0;   // becomes local cursor
    }
    __syncthreads();
    for (int e = e0 + tid; e < e1; e += 256) {
        int s = srcI[e], d = dstI[e];
        int b = d >> NBSHIFT;
        int pos = lbase[b] + atomicAdd(&lcnt[b], 1);
        tmp[pos] = make_int2(s, d);
        s = srcD[e]; d = N + dstD[e];
        b = d >> NBSHIFT;
        pos = lbase[b] + atomicAdd(&lcnt[b], 1);
        tmp[pos] = make_int2(s, d);
    }
}

// fine scatter: coalesced read of coarse-sorted edges; writes stay L2-local
__global__ __launch_bounds__(256) void fine_scatter(
    const int2* __restrict__ tmp, int* cur,
    const float* __restrict__ dI, const float* __restrict__ dD,
    int2* __restrict__ edg, int N, int E2) {
    int stride = gridDim.x * 256;
    for (int e = blockIdx.x * 256 + threadIdx.x; e < E2; e += stride) {
        int2 t = tmp[e];
        int s = t.x, d = t.y;
        int pos = atomicAdd(&cur[d], 1);
        float coef = (d < N) ? dI[s] * dI[d] : dD[s] * dD[d - N];
        edg[pos] = make_int2(s, __float_as_int(coef));
    }
}

// ---------------- gather: one wave per node, bf16 xl rows, 8-deep ILP ----------------
__global__ __launch_bounds__(256) void gather_combine3(
    const ushort_t* __restrict__ xlb,
    const int* __restrict__ off, const int2* __restrict__ edg,
    const float* __restrict__ dI, const float* __restrict__ dD,
    const float* __restrict__ bconv,
    ushort_t* __restrict__ zh, int N, int E2) {
    int d = blockIdx.x * 4 + (threadIdx.x >> 6);
    int lane = threadIdx.x & 63;
    if (d >= N) return;
    const uint_t* x2 = (const uint_t*)xlb;
    uint_t xdp = x2[(long)d * 64 + lane];
    float xdx = bf2f((ushort_t)(xdp & 0xffff)), xdy = bf2f((ushort_t)(xdp >> 16));
    float aI = dI[d], aD = dD[d];
    float2 accI, accD;
    {
        float c = aI * aI;
        accI.x = c * xdx; accI.y = c * xdy;
        c = aD * aD;
        accD.x = c * xdx; accD.y = c * xdy;
    }
#pragma unroll
    for (int g = 0; g < 2; ++g) {
        int s0 = (g == 0) ? off[d] : off[N + d];
        int e0 = (g == 0) ? off[d + 1] : ((d == N - 1) ? E2 : off[N + d + 1]);
        float2 a0 = {0.f, 0.f}, a1 = {0.f, 0.f}, a2 = {0.f, 0.f}, a3 = {0.f, 0.f};
        float2 a4 = {0.f, 0.f}, a5 = {0.f, 0.f}, a6 = {0.f, 0.f}, a7 = {0.f, 0.f};
        for (int k0 = s0; k0 < e0; k0 += 64) {
            int nk = min(64, e0 - k0);
            int2 ec = (lane < nk) ? edg[k0 + lane] : make_int2(0, 0);
            int sv = ec.x;
            float cv = __int_as_float(ec.y);
            for (int k = 0; k < nk; k += 8) {
                int i0 = __builtin_amdgcn_readlane(sv, k);
                int i1 = __builtin_amdgcn_readlane(sv, k + 1);
                int i2 = __builtin_amdgcn_readlane(sv, k + 2);
                int i3 = __builtin_amdgcn_readlane(sv, k + 3);
                int i4 = __builtin_amdgcn_readlane(sv, k + 4);
                int i5 = __builtin_amdgcn_readlane(sv, k + 5);
                int i6 = __builtin_amdgcn_readlane(sv, k + 6);
                int i7 = __builtin_amdgcn_readlane(sv, k + 7);
                uint_t p0 = x2[(long)i0 * 64 + lane];
                uint_t p1 = x2[(long)i1 * 64 + lane];
                uint_t p2 = x2[(long)i2 * 64 + lane];
                uint_t p3 = x2[(long)i3 * 64 + lane];
                uint_t p4 = x2[(long)i4 * 64 + lane];
                uint_t p5 = x2[(long)i5 * 64 + lane];
                uint_t p6 = x2[(long)i6 * 64 + lane];
                uint_t p7 = x2[(long)i7 * 64 + lane];
                float c0 = readlane_f(cv, k);
                float c1 = readlane_f(cv, k + 1);
                float c2 = readlane_f(cv, k + 2);
                float c3 = readlane_f(cv, k + 3);
                float c4 = readlane_f(cv, k + 4);
                float c5 = readlane_f(cv, k + 5);
                float c6 = readlane_f(cv, k + 6);
                float c7 = readlane_f(cv, k + 7);
                a0.x = fmaf(c0, bf2f((ushort_t)(p0 & 0xffff)), a0.x);
                a0.y = fmaf(c0, bf2f((ushort_t)(p0 >> 16)), a0.y);
                a1.x = fmaf(c1, bf2f((ushort_t)(p1 & 0xffff)), a1.x);
                a1.y = fmaf(c1, bf2f((ushort_t)(p1 >> 16)), a1.y);
                a2.x = fmaf(c2, bf2f((ushort_t)(p2 & 0xffff)), a2.x);
                a2.y = fmaf(c2, bf2f((ushort_t)(p2 >> 16)), a2.y);
                a3.x = fmaf(c3, bf2f((ushort_t)(p3 & 0xffff)), a3.x);
                a3.y = fmaf(c3, bf2f((ushort_t)(p3 >> 16)), a3.y);
                a4.x = fmaf(c4, bf2f((ushort_t)(p4 & 0xffff)), a4.x);
                a4.y = fmaf(c4, bf2f((ushort_t)(p4 >> 16)), a4.y);
                a5.x = fmaf(c5, bf2f((ushort_t)(p5 & 0xffff)), a5.x);
                a5.y = fmaf(c5, bf2f((ushort_t)(p5 >> 16)), a5.y);
                a6.x = fmaf(c6, bf2f((ushort_t)(p6 & 0xffff)), a6.x);
                a6.y = fmaf(c6, bf2f((ushort_t)(p6 >> 16)), a6.y);
                a7.x = fmaf(c7, bf2f((ushort_t)(p7 & 0xffff)), a7.x);
                a7.y = fmaf(c7, bf2f((ushort_t)(p7 >> 16)), a7.y);
            }
        }
        float sx = ((a0.x + a1.x) + (a2.x + a3.x)) + ((a4.x + a5.x) + (a6.x + a7.x));
        float sy = ((a0.y + a1.y) + (a2.y + a3.y)) + ((a4.y + a5.y) + (a6.y + a7.y));
        if (g == 0) { accI.x += sx; accI.y += sy; }
        else        { accD.x += sx; accD.y += sy; }
    }
    float2 b = ((const float2*)bconv)[lane];
    float rx = fmaxf(accI.x + b.x, 0.f) + fmaxf(accD.x + b.x, 0.f);
    float ry = fmaxf(accI.y + b.y, 0.f) + fmaxf(accD.y + b.y, 0.f);
    ushort_t hx = f2bf(rx), hy = f2bf(ry);
    ((uint_t*)zh)[(long)d * 64 + lane] = (uint_t)hx | ((uint_t)hy << 16);
}

// ---------------- decode: half-K ping-pong (2x16KB LDS -> 4 blocks/CU) ----------------
// out[p] = relu( zi@W1a + zj@W1b + |zi-zj|@W1c + b1 ) @ W2 + b2
// 6 stages: (a,h0)(a,h1)(b,h0)(b,h1)(c,h0)(c,h1); d computed in place after zi phases.
__global__ __launch_bounds__(512) void decode_mfma8(
    const ushort_t* __restrict__ zh,
    const int* __restrict__ ei, const int* __restrict__ ej,
    const ushort_t* __restrict__ w1f,
    const float* __restrict__ b1, const float* __restrict__ W2, const float* __restrict__ b2,
    float* __restrict__ out, int P) {
    __shared__ ushort_t Wlds[2][8192];    // 2 x 16 KB ping-pong
    int tid = threadIdx.x;
    int lane = tid & 63, w = tid >> 6;    // w in 0..7
    int r = lane & 15, q = lane >> 4;
    int base = blockIdx.x * 128 + w * 16;
    bool active = base < P;
    int iv = 0, jv = 0;
    if (active && lane < 16) {
        int p = min(base + lane, P - 1);
        iv = ei[p]; jv = ej[p];
    }
    // divergent lane index -> __shfl (ds_bpermute), NOT readlane
    int myi = __shfl(iv, r, 64);
    int myj = __shfl(jv, r, 64);

    short8 zih[4], zjh[4];
    if (active) {
        const ushort_t* pih = zh + (long)myi * 128 + q * 8;
        const ushort_t* pjh = zh + (long)myj * 128 + q * 8;
#pragma unroll
        for (int kk = 0; kk < 4; ++kk) {
            zih[kk] = *(const short8*)(pih + kk * 32);
            zjh[kk] = *(const short8*)(pjh + kk * 32);
        }
    }

    // stage (m=0,h=0) -> buf 0 (16KB = 1024 float4; 512 thr x 2)
    {
        const float4* s4 = (const float4*)w1f;
        float4* d4 = (float4*)Wlds[0];
#pragma unroll
        for (int t2 = 0; t2 < 2; ++t2) d4[t2 * 512 + tid] = s4[t2 * 512 + tid];
    }
    __syncthreads();

    f32x4 acc[8] = {};

#define COMPUTE(buf, A0, A1)                                                    \
    if (active) {                                                               \
        _Pragma("unroll")                                                       \
        for (int t = 0; t < 8; ++t) {                                           \
            short8 b0 = *(const short8*)&Wlds[buf][(t * 2 + 0) * 512 + lane * 8]; \
            acc[t] = __builtin_amdgcn_mfma_f32_16x16x32_bf16(A0, b0, acc[t], 0, 0, 0); \
            short8 b1v = *(const short8*)&Wlds[buf][(t * 2 + 1) * 512 + lane * 8]; \
            acc[t] = __builtin_amdgcn_mfma_f32_16x16x32_bf16(A1, b1v, acc[t], 0, 0, 0); \
        }                                                                       \
    }

#define PREFETCH(stg)                                                           \
    {                                                                           \
        const float4* s4 = (const float4*)(w1f + (stg) * 8192);                 \
        pre[0] = s4[tid];                                                       \
        pre[1] = s4[512 + tid];                                                 \
    }

#define WRITEBUF(buf)                                                           \
    {                                                                           \
        float4* d4 = (float4*)Wlds[buf];                                        \
        d4[tid] = pre[0];                                                       \
        d4[512 + tid] = pre[1];                                                 \
    }

    float4 pre[2];
    PREFETCH(1);                      // (a, h1)
    COMPUTE(0, zih[0], zih[1]);       // zi @ W1a half0
    WRITEBUF(1);
    __syncthreads();

    PREFETCH(2);                      // (b, h0)
    COMPUTE(1, zih[2], zih[3]);       // zi @ W1a half1
    // d = |zi - zj| in place (zi consumed; zjh intact for phase b)
    if (active) {
#pragma unroll
        for (int kk = 0; kk < 4; ++kk) {
#pragma unroll
            for (int e = 0; e < 8; ++e) {
                float a = bf2f((ushort_t)zih[kk][e]);
                float b = bf2f((ushort_t)zjh[kk][e]);
                zih[kk][e] = (short)f2bf(fabsf(a - b));
            }
        }
    }
    WRITEBUF(0);
    __syncthreads();

    PREFETCH(3);                      // (b, h1)
    COMPUTE(0, zjh[0], zjh[1]);       // zj @ W1b half0
    WRITEBUF(1);
    __syncthreads();

    PREFETCH(4);                      // (c, h0)
    COMPUTE(1, zjh[2], zjh[3]);       // zj @ W1b half1
    WRITEBUF(0);
    __syncthreads();

    PREFETCH(5);                      // (c, h1)
    COMPUTE(0, zih[0], zih[1]);       // d @ W1c half0
    WRITEBUF(1);
    __syncthreads();

    COMPUTE(1, zih[2], zih[3]);       // d @ W1c half1
#undef COMPUTE
#undef PREFETCH
#undef WRITEBUF

    if (!active) return;
    float b2v = b2[0];
    float b1c[8], w2c[8];
#pragma unroll
    for (int t = 0; t < 8; ++t) {
        int col = 16 * t + r;
        b1c[t] = b1[col];
        w2c[t] = W2[col];
    }
#pragma unroll
    for (int r2 = 0; r2 < 4; ++r2) {
        int row = q * 4 + r2;                 // C layout: row = (lane>>4)*4 + reg
        float s = 0.f;
#pragma unroll
        for (int t = 0; t < 8; ++t) {
            float h = acc[t][r2] + b1c[t];    // col = 16t + (lane&15)
            s += fmaxf(h, 0.f) * w2c[t];
        }
        s += __shfl_xor(s, 1, 64);
        s += __shfl_xor(s, 2, 64);
        s += __shfl_xor(s, 4, 64);
        s += __shfl_xor(s, 8, 64);
        int gp = base + row;
        if (r == 0 && gp < P) out[gp] = s + b2v;
    }
}

extern "C" void kernel_launch(void* const* d_in, const int* in_sizes, int n_in,
                              void* d_out, int out_size, void* d_ws, size_t ws_size,
                              hipStream_t stream) {
    const float* x  = (const float*)d_in[0];
    const int*   eI = (const int*)d_in[1];
    const int*   eD = (const int*)d_in[2];
    const int*   eL = (const int*)d_in[3];
    const float* Wconv = (const float*)d_in[4];
    const float* bconv = (const float*)d_in[5];
    const float* W1 = (const float*)d_in[6];
    const float* b1 = (const float*)d_in[7];
    const float* W2 = (const float*)d_in[8];
    const float* b2 = (const float*)d_in[9];

    int N = in_sizes[0] / 256;
    int E = in_sizes[1] / 2;
    int P = in_sizes[3] / 2;
    long NH = (long)N * 128;
    int n2 = 2 * N;
    int NB = (n2 + 127) >> NBSHIFT;   // coarse buckets (<=1024)

    // ---- workspace layout ----
    float* ws = (float*)d_ws;
    ushort_t* xlb = (ushort_t*)ws;          // N*128 ushort (bf16 xl)
    ushort_t* zh = xlb + NH;                // N*128 ushort (bf16 z)
    float* dI = (float*)(zh + NH);          // N
    float* dD = dI + N;                     // N
    int* iws = (int*)(dD + N);
    int* cnt = iws;                 // 2N
    int* off = cnt + n2;            // 2N
    int* cur = off + n2;            // 2N
    int nb = (n2 + 255) / 256;
    int* partials = cur + n2;       // padded to 64 ints
    int* ccnt = partials + ((nb + 63) & ~63);   // 1024
    int* gcur = ccnt + 1024;                    // 1024
    int2* edg = (int2*)(gcur + 1024);           // 2E int2 (final {src,coef})
    int2* tmp = edg + 2 * (long)E;              // 2E int2 (coarse-sorted {src,dst'})
    ushort_t* w1f = (ushort_t*)(tmp + 2 * (long)E);  // 3*16384
    ushort_t* btch = w1f + 3 * 16384;                // 32768
    ushort_t* btcl = btch + 32768;                   // 32768
    float* out = (float*)d_out;

    // weight preps
    prep_bt_conv<<<128, 256, 0, stream>>>(Wconv, btch, btcl);
    prep_w1frag2<<<192, 256, 0, stream>>>(W1, w1f);

    // xl = bf16(x @ W_conv)
    dim3 gx((N + 127) / 128, 1);
    gemm_mfma_hilo_bf16<<<gx, 256, 0, stream>>>(x, btch, btcl, xlb, N, 256, 128);

    // CSR build: fine degree counts + offsets
    zero_ints<<<(n2 + 255) / 256, 256, 0, stream>>>(cnt, n2);
    zero_ints<<<4, 256, 0, stream>>>(ccnt, 1024);
    count_deg<<<(E + 255) / 256, 256, 0, stream>>>(eI + E, eD + E, cnt, N, E);
    scan_partial<<<nb, 256, 0, stream>>>(cnt, partials, n2);
    scan_partials_excl2<<<1, 512, 0, stream>>>(partials, nb);
    scan_final<<<nb, 256, 0, stream>>>(cnt, partials, off, cur, dI, dD, N, n2);

    // two-level edge sort
    coarse_count<<<256, 256, 0, stream>>>(eI + E, eD + E, ccnt, N, E, NB);
    coarse_scan<<<1, 1024, 0, stream>>>(ccnt, gcur, NB);
    coarse_scatter2<<<256, 256, 0, stream>>>(eI, eI + E, eD, eD + E, gcur, tmp, N, E, NB);
    fine_scatter<<<1024, 256, 0, stream>>>(tmp, cur, dI, dD, edg, N, 2 * E);

    // gather + combine -> bf16 z
    gather_combine3<<<(N + 3) / 4, 256, 0, stream>>>(xlb, off, edg, dI, dD,
                                                     bconv, zh, N, 2 * E);

    // decode (half-K ping-pong, 32KB LDS -> 4 blocks/CU)
    decode_mfma8<<<(P + 127) / 128, 512, 0, stream>>>(zh, eL, eL + P, w1f,
                                                      b1, W2, b2, out, P);
}

// Round 25
// 328.945 us; speedup vs baseline: 1.0240x; 1.0240x over previous
//
#include <hip/hip_runtime.h>

typedef short short8 __attribute__((ext_vector_type(8)));
typedef float f32x4 __attribute__((ext_vector_type(4)));
typedef float f32x16 __attribute__((ext_vector_type(16)));
typedef unsigned short ushort_t;
typedef unsigned int uint_t;

#define HD __device__ __forceinline__
#define NBSHIFT 7   // coarse bucket = 128 combined-dst values

HD ushort_t f2bf(float f) {  // round-to-nearest-even f32 -> bf16 bits
    uint_t u = __float_as_uint(f);
    uint_t r = (u + 0x7fffu + ((u >> 16) & 1u)) >> 16;
    return (ushort_t)r;
}
HD float bf2f(ushort_t h) { return __uint_as_float(((uint_t)h) << 16); }
HD float readlane_f(float v, int l) {
    return __int_as_float(__builtin_amdgcn_readlane(__float_as_int(v), l));
}

// ---------------- MFMA hi/lo split GEMM: C[M,Ntot] = A[M,K] @ B, bf16 output ----------------
__global__ __launch_bounds__(256) void gemm_mfma_hilo_bf16(
    const float* __restrict__ A, const ushort_t* __restrict__ Bth,
    const ushort_t* __restrict__ Btl, ushort_t* __restrict__ C,
    int M, int K, int Ntot) {
    __shared__ ushort_t Ah[128][72], Al[128][72], Bh[128][72], Bl[128][72];
    int tid = threadIdx.x;
    int lane = tid & 63, w = tid >> 6;
    int row0 = blockIdx.x * 128;
    int col0 = blockIdx.y * 128;
    int cl = lane & 31, hi = lane >> 5;
    f32x16 acc[4] = {};
    for (int k0 = 0; k0 < K; k0 += 64) {
        for (int e = tid; e < 4096; e += 256) {
            int r = e >> 5, k2 = e & 31;
            int gr = row0 + r;
            float2 v = {0.f, 0.f};
            if (gr < M) v = *(const float2*)&A[(long)gr * K + k0 + k2 * 2];
            ushort_t h0 = f2bf(v.x); ushort_t l0 = f2bf(v.x - bf2f(h0));
            ushort_t h1 = f2bf(v.y); ushort_t l1 = f2bf(v.y - bf2f(h1));
            *(uint_t*)&Ah[r][k2 * 2] = (uint_t)h0 | ((uint_t)h1 << 16);
            *(uint_t*)&Al[r][k2 * 2] = (uint_t)l0 | ((uint_t)l1 << 16);
        }
        for (int e = tid; e < 4096; e += 256) {
            int n = e >> 5, k2 = e & 31;
            const uint_t* ph = (const uint_t*)&Bth[(long)(col0 + n) * K + k0];
            const uint_t* pl = (const uint_t*)&Btl[(long)(col0 + n) * K + k0];
            *(uint_t*)&Bh[n][k2 * 2] = ph[k2];
            *(uint_t*)&Bl[n][k2 * 2] = pl[k2];
        }
        __syncthreads();
        int arow = w * 32 + cl;
#pragma unroll
        for (int kk = 0; kk < 4; ++kk) {
            int koff = kk * 16 + hi * 8;
            short8 a_h = *(const short8*)&Ah[arow][koff];
            short8 a_l = *(const short8*)&Al[arow][koff];
#pragma unroll
            for (int nf = 0; nf < 4; ++nf) {
                int bcol = nf * 32 + cl;
                short8 b_h = *(const short8*)&Bh[bcol][koff];
                short8 b_l = *(const short8*)&Bl[bcol][koff];
                acc[nf] = __builtin_amdgcn_mfma_f32_32x32x16_bf16(a_h, b_h, acc[nf], 0, 0, 0);
                acc[nf] = __builtin_amdgcn_mfma_f32_32x32x16_bf16(a_l, b_h, acc[nf], 0, 0, 0);
                acc[nf] = __builtin_amdgcn_mfma_f32_32x32x16_bf16(a_h, b_l, acc[nf], 0, 0, 0);
            }
        }
        __syncthreads();
    }
#pragma unroll
    for (int nf = 0; nf < 4; ++nf) {
#pragma unroll
        for (int reg = 0; reg < 16; ++reg) {
            int crow = (reg & 3) + 8 * (reg >> 2) + 4 * hi + w * 32;
            int gr = row0 + crow;
            if (gr < M) C[(long)gr * Ntot + col0 + nf * 32 + cl] = f2bf(acc[nf][reg]);
        }
    }
}

// ---------------- weight prep ----------------
__global__ void prep_bt_conv(const float* __restrict__ Wc, ushort_t* bh, ushort_t* bl) {
    int idx = blockIdx.x * 256 + threadIdx.x;
    if (idx >= 128 * 256) return;
    int n = idx >> 8, k = idx & 255;
    float v = Wc[k * 128 + n];
    ushort_t h = f2bf(v);
    bh[idx] = h;
    bl[idx] = f2bf(v - bf2f(h));
}

// W1 (a,b,c blocks) in MFMA B-fragment order, bf16-hi only
__global__ void prep_w1frag(const float* __restrict__ W1, ushort_t* __restrict__ w1f) {
    int idx = blockIdx.x * 256 + threadIdx.x;
    if (idx >= 3 * 16384) return;
    int m = idx >> 14;
    int rem = idx & 16383;
    int f = rem >> 9, l = (rem >> 3) & 63, e = rem & 7;
    int t = f >> 2, kk = f & 3;
    int col = 16 * t + (l & 15);
    int k = kk * 32 + (l >> 4) * 8 + e;
    w1f[idx] = f2bf(W1[(m * 128 + k) * 128 + col]);
}

// ---------------- CSR build ----------------
__global__ void zero_ints(int* p, int n) {
    int i = blockIdx.x * 256 + threadIdx.x;
    if (i < n) p[i] = 0;
}

__global__ void count_deg(const int* __restrict__ dstI, const int* __restrict__ dstD,
                          int* cnt, int N, int E) {
    int e = blockIdx.x * 256 + threadIdx.x;
    if (e < E) {
        atomicAdd(&cnt[dstI[e]], 1);
        atomicAdd(&cnt[N + dstD[e]], 1);
    }
}

__global__ void scan_partial(const int* __restrict__ cnt, int* partials, int n2) {
    __shared__ int sdata[256];
    int i = blockIdx.x * 256 + threadIdx.x;
    sdata[threadIdx.x] = (i < n2) ? cnt[i] : 0;
    __syncthreads();
    for (int s = 128; s > 0; s >>= 1) {
        if (threadIdx.x < s) sdata[threadIdx.x] += sdata[threadIdx.x + s];
        __syncthreads();
    }
    if (threadIdx.x == 0) partials[blockIdx.x] = sdata[0];
}

__global__ void scan_partials_excl2(int* partials, int nb) {
    __shared__ int sd[512];
    int t = threadIdx.x;
    int v = (t < nb) ? partials[t] : 0;
    sd[t] = v;
    __syncthreads();
    for (int s = 1; s < 512; s <<= 1) {
        int u = (t >= s) ? sd[t - s] : 0;
        __syncthreads();
        sd[t] += u;
        __syncthreads();
    }
    if (t < nb) partials[t] = sd[t] - v;   // exclusive
}

__global__ void scan_final(const int* __restrict__ cnt, const int* __restrict__ partials,
                           int* off, int* cur, float* dI, float* dD, int N, int n2) {
    __shared__ int sdata[256];
    int i = blockIdx.x * 256 + threadIdx.x;
    int v = (i < n2) ? cnt[i] : 0;
    sdata[threadIdx.x] = v;
    __syncthreads();
    for (int s = 1; s < 256; s <<= 1) {
        int t = (threadIdx.x >= s) ? sdata[threadIdx.x - s] : 0;
        __syncthreads();
        sdata[threadIdx.x] += t;
        __syncthreads();
    }
    int excl = sdata[threadIdx.x] - v + partials[blockIdx.x];
    if (i < n2) {
        off[i] = excl; cur[i] = excl;
        float dv = rsqrtf((float)(v + 1));
        if (i < N) dI[i] = dv; else dD[i - N] = dv;
    }
}

// ---- two-level edge sort ----
__global__ __launch_bounds__(256) void coarse_count(
    const int* __restrict__ dstI, const int* __restrict__ dstD,
    int* __restrict__ ccnt, int N, int E, int NB) {
    __shared__ int bins[1024];
    for (int b = threadIdx.x; b < NB; b += 256) bins[b] = 0;
    __syncthreads();
    int stride = gridDim.x * 256;
    for (int e = blockIdx.x * 256 + threadIdx.x; e < E; e += stride) {
        atomicAdd(&bins[dstI[e] >> NBSHIFT], 1);
        atomicAdd(&bins[(N + dstD[e]) >> NBSHIFT], 1);
    }
    __syncthreads();
    for (int b = threadIdx.x; b < NB; b += 256) {
        int v = bins[b];
        if (v) atomicAdd(&ccnt[b], v);
    }
}

__global__ void coarse_scan(const int* __restrict__ ccnt, int* gcur, int NB) {
    __shared__ int sd[1024];
    int t = threadIdx.x;
    int v = (t < NB) ? ccnt[t] : 0;
    sd[t] = v;
    __syncthreads();
    for (int s = 1; s < 1024; s <<= 1) {
        int u = (t >= s) ? sd[t - s] : 0;
        __syncthreads();
        sd[t] += u;
        __syncthreads();
    }
    if (t < NB) gcur[t] = sd[t] - v;
}

// block-aggregated coarse scatter (1 global atomic per block,bucket)
__global__ __launch_bounds__(256) void coarse_scatter2(
    const int* __restrict__ srcI, const int* __restrict__ dstI,
    const int* __restrict__ srcD, const int* __restrict__ dstD,
    int* __restrict__ gcur, int2* __restrict__ tmp, int N, int E, int NB) {
    __shared__ int lcnt[1024];
    __shared__ int lbase[1024];
    int tid = threadIdx.x;
    int chunk = (E + gridDim.x - 1) / gridDim.x;
    int e0 = blockIdx.x * chunk;
    int e1 = min(e0 + chunk, E);
    for (int b = tid; b < NB; b += 256) lcnt[b] = 0;
    __syncthreads();
    for (int e = e0 + tid; e < e1; e += 256) {
        atomicAdd(&lcnt[dstI[e] >> NBSHIFT], 1);
        atomicAdd(&lcnt[(N + dstD[e]) >> NBSHIFT], 1);
    }
    __syncthreads();
    for (int b = tid; b < NB; b += 256) {
        int c = lcnt[b];
        lbase[b] = c ? atomicAdd(&gcur[b], c) : 0;
        lcnt[b] = 0;   // becomes local cursor
    }
    __syncthreads();
    for (int e = e0 + tid; e < e1; e += 256) {
        int s = srcI[e], d = dstI[e];
        int b = d >> NBSHIFT;
        int pos = lbase[b] + atomicAdd(&lcnt[b], 1);
        tmp[pos] = make_int2(s, d);
        s = srcD[e]; d = N + dstD[e];
        b = d >> NBSHIFT;
        pos = lbase[b] + atomicAdd(&lcnt[b], 1);
        tmp[pos] = make_int2(s, d);
    }
}

// fine scatter: coalesced read of coarse-sorted edges; writes stay L2-local
__global__ __launch_bounds__(256) void fine_scatter(
    const int2* __restrict__ tmp, int* cur,
    const float* __restrict__ dI, const float* __restrict__ dD,
    int2* __restrict__ edg, int N, int E2) {
    int stride = gridDim.x * 256;
    for (int e = blockIdx.x * 256 + threadIdx.x; e < E2; e += stride) {
        int2 t = tmp[e];
        int s = t.x, d = t.y;
        int pos = atomicAdd(&cur[d], 1);
        float coef = (d < N) ? dI[s] * dI[d] : dD[s] * dD[d - N];
        edg[pos] = make_int2(s, __float_as_int(coef));
    }
}

// ---------------- gather: one wave per node, bf16 xl rows, 8-deep ILP ----------------
__global__ __launch_bounds__(256) void gather_combine3(
    const ushort_t* __restrict__ xlb,
    const int* __restrict__ off, const int2* __restrict__ edg,
    const float* __restrict__ dI, const float* __restrict__ dD,
    const float* __restrict__ bconv,
    ushort_t* __restrict__ zh, int N, int E2) {
    int d = blockIdx.x * 4 + (threadIdx.x >> 6);
    int lane = threadIdx.x & 63;
    if (d >= N) return;
    const uint_t* x2 = (const uint_t*)xlb;
    uint_t xdp = x2[(long)d * 64 + lane];
    float xdx = bf2f((ushort_t)(xdp & 0xffff)), xdy = bf2f((ushort_t)(xdp >> 16));
    float aI = dI[d], aD = dD[d];
    float2 accI, accD;
    {
        float c = aI * aI;
        accI.x = c * xdx; accI.y = c * xdy;
        c = aD * aD;
        accD.x = c * xdx; accD.y = c * xdy;
    }
#pragma unroll
    for (int g = 0; g < 2; ++g) {
        int s0 = (g == 0) ? off[d] : off[N + d];
        int e0 = (g == 0) ? off[d + 1] : ((d == N - 1) ? E2 : off[N + d + 1]);
        float2 a0 = {0.f, 0.f}, a1 = {0.f, 0.f}, a2 = {0.f, 0.f}, a3 = {0.f, 0.f};
        float2 a4 = {0.f, 0.f}, a5 = {0.f, 0.f}, a6 = {0.f, 0.f}, a7 = {0.f, 0.f};
        for (int k0 = s0; k0 < e0; k0 += 64) {
            int nk = min(64, e0 - k0);
            int2 ec = (lane < nk) ? edg[k0 + lane] : make_int2(0, 0);
            int sv = ec.x;
            float cv = __int_as_float(ec.y);
            for (int k = 0; k < nk; k += 8) {
                int i0 = __builtin_amdgcn_readlane(sv, k);
                int i1 = __builtin_amdgcn_readlane(sv, k + 1);
                int i2 = __builtin_amdgcn_readlane(sv, k + 2);
                int i3 = __builtin_amdgcn_readlane(sv, k + 3);
                int i4 = __builtin_amdgcn_readlane(sv, k + 4);
                int i5 = __builtin_amdgcn_readlane(sv, k + 5);
                int i6 = __builtin_amdgcn_readlane(sv, k + 6);
                int i7 = __builtin_amdgcn_readlane(sv, k + 7);
                uint_t p0 = x2[(long)i0 * 64 + lane];
                uint_t p1 = x2[(long)i1 * 64 + lane];
                uint_t p2 = x2[(long)i2 * 64 + lane];
                uint_t p3 = x2[(long)i3 * 64 + lane];
                uint_t p4 = x2[(long)i4 * 64 + lane];
                uint_t p5 = x2[(long)i5 * 64 + lane];
                uint_t p6 = x2[(long)i6 * 64 + lane];
                uint_t p7 = x2[(long)i7 * 64 + lane];
                float c0 = readlane_f(cv, k);
                float c1 = readlane_f(cv, k + 1);
                float c2 = readlane_f(cv, k + 2);
                float c3 = readlane_f(cv, k + 3);
                float c4 = readlane_f(cv, k + 4);
                float c5 = readlane_f(cv, k + 5);
                float c6 = readlane_f(cv, k + 6);
                float c7 = readlane_f(cv, k + 7);
                a0.x = fmaf(c0, bf2f((ushort_t)(p0 & 0xffff)), a0.x);
                a0.y = fmaf(c0, bf2f((ushort_t)(p0 >> 16)), a0.y);
                a1.x = fmaf(c1, bf2f((ushort_t)(p1 & 0xffff)), a1.x);
                a1.y = fmaf(c1, bf2f((ushort_t)(p1 >> 16)), a1.y);
                a2.x = fmaf(c2, bf2f((ushort_t)(p2 & 0xffff)), a2.x);
                a2.y = fmaf(c2, bf2f((ushort_t)(p2 >> 16)), a2.y);
                a3.x = fmaf(c3, bf2f((ushort_t)(p3 & 0xffff)), a3.x);
                a3.y = fmaf(c3, bf2f((ushort_t)(p3 >> 16)), a3.y);
                a4.x = fmaf(c4, bf2f((ushort_t)(p4 & 0xffff)), a4.x);
                a4.y = fmaf(c4, bf2f((ushort_t)(p4 >> 16)), a4.y);
                a5.x = fmaf(c5, bf2f((ushort_t)(p5 & 0xffff)), a5.x);
                a5.y = fmaf(c5, bf2f((ushort_t)(p5 >> 16)), a5.y);
                a6.x = fmaf(c6, bf2f((ushort_t)(p6 & 0xffff)), a6.x);
                a6.y = fmaf(c6, bf2f((ushort_t)(p6 >> 16)), a6.y);
                a7.x = fmaf(c7, bf2f((ushort_t)(p7 & 0xffff)), a7.x);
                a7.y = fmaf(c7, bf2f((ushort_t)(p7 >> 16)), a7.y);
            }
        }
        float sx = ((a0.x + a1.x) + (a2.x + a3.x)) + ((a4.x + a5.x) + (a6.x + a7.x));
        float sy = ((a0.y + a1.y) + (a2.y + a3.y)) + ((a4.y + a5.y) + (a6.y + a7.y));
        if (g == 0) { accI.x += sx; accI.y += sy; }
        else        { accD.x += sx; accD.y += sy; }
    }
    float2 b = ((const float2*)bconv)[lane];
    float rx = fmaxf(accI.x + b.x, 0.f) + fmaxf(accD.x + b.x, 0.f);
    float ry = fmaxf(accI.y + b.y, 0.f) + fmaxf(accD.y + b.y, 0.f);
    ushort_t hx = f2bf(rx), hy = f2bf(ry);
    ((uint_t*)zh)[(long)d * 64 + lane] = (uint_t)hx | ((uint_t)hy << 16);
}

// ---------------- decode: 8-wave blocks, ping-pong W staging, bf16-only z ----------------
__global__ __launch_bounds__(512) void decode_mfma7(
    const ushort_t* __restrict__ zh,
    const int* __restrict__ ei, const int* __restrict__ ej,
    const ushort_t* __restrict__ w1f,
    const float* __restrict__ b1, const float* __restrict__ W2, const float* __restrict__ b2,
    float* __restrict__ out, int P) {
    __shared__ ushort_t Wlds[2][16384];   // 64 KB ping-pong
    int tid = threadIdx.x;
    int lane = tid & 63, w = tid >> 6;
    int r = lane & 15, q = lane >> 4;
    int base = blockIdx.x * 128 + w * 16;
    bool active = base < P;
    int iv = 0, jv = 0;
    if (active && lane < 16) {
        int p = min(base + lane, P - 1);
        iv = ei[p]; jv = ej[p];
    }
    // divergent lane index -> __shfl (ds_bpermute), NOT readlane
    int myi = __shfl(iv, r, 64);
    int myj = __shfl(jv, r, 64);

    short8 zih[4], zjh[4];
    if (active) {
        const ushort_t* pih = zh + (long)myi * 128 + q * 8;
        const ushort_t* pjh = zh + (long)myj * 128 + q * 8;
#pragma unroll
        for (int kk = 0; kk < 4; ++kk) {
            zih[kk] = *(const short8*)(pih + kk * 32);
            zjh[kk] = *(const short8*)(pjh + kk * 32);
        }
    }

    {
        const float4* s4 = (const float4*)w1f;
        float4* d4 = (float4*)Wlds[0];
#pragma unroll
        for (int t2 = 0; t2 < 4; ++t2) d4[t2 * 512 + tid] = s4[t2 * 512 + tid];
    }
    __syncthreads();

    f32x4 acc[8] = {};

#define COMPUTE(buf, AH)                                                        \
    if (active) {                                                               \
        _Pragma("unroll")                                                       \
        for (int t = 0; t < 8; ++t) {                                           \
            _Pragma("unroll")                                                   \
            for (int kk = 0; kk < 4; ++kk) {                                    \
                short8 bh = *(const short8*)&Wlds[buf][(t * 4 + kk) * 512 + lane * 8]; \
                acc[t] = __builtin_amdgcn_mfma_f32_16x16x32_bf16(AH[kk], bh, acc[t], 0, 0, 0); \
            }                                                                   \
        }                                                                       \
    }

    float4 pre[4];
    {
        const float4* s4 = (const float4*)(w1f + 16384);
#pragma unroll
        for (int t2 = 0; t2 < 4; ++t2) pre[t2] = s4[t2 * 512 + tid];
    }
    COMPUTE(0, zih);            // zi @ W1a
    {
        float4* d4 = (float4*)Wlds[1];
#pragma unroll
        for (int t2 = 0; t2 < 4; ++t2) d4[t2 * 512 + tid] = pre[t2];
    }
    __syncthreads();

    {
        const float4* s4 = (const float4*)(w1f + 2 * 16384);
#pragma unroll
        for (int t2 = 0; t2 < 4; ++t2) pre[t2] = s4[t2 * 512 + tid];
    }
    COMPUTE(1, zjh);            // zj @ W1b
    if (active) {
#pragma unroll
        for (int kk = 0; kk < 4; ++kk) {
#pragma unroll
            for (int e = 0; e < 8; ++e) {
                float a = bf2f((ushort_t)zih[kk][e]);
                float b = bf2f((ushort_t)zjh[kk][e]);
                zih[kk][e] = (short)f2bf(fabsf(a - b));
            }
        }
    }
    {
        float4* d4 = (float4*)Wlds[0];
#pragma unroll
        for (int t2 = 0; t2 < 4; ++t2) d4[t2 * 512 + tid] = pre[t2];
    }
    __syncthreads();

    COMPUTE(0, zih);            // |zi-zj| @ W1c
#undef COMPUTE

    if (!active) return;
    float b2v = b2[0];
    float b1c[8], w2c[8];
#pragma unroll
    for (int t = 0; t < 8; ++t) {
        int col = 16 * t + r;
        b1c[t] = b1[col];
        w2c[t] = W2[col];
    }
#pragma unroll
    for (int r2 = 0; r2 < 4; ++r2) {
        int row = q * 4 + r2;                 // C layout: row = (lane>>4)*4 + reg
        float s = 0.f;
#pragma unroll
        for (int t = 0; t < 8; ++t) {
            float h = acc[t][r2] + b1c[t];    // col = 16t + (lane&15)
            s += fmaxf(h, 0.f) * w2c[t];
        }
        s += __shfl_xor(s, 1, 64);
        s += __shfl_xor(s, 2, 64);
        s += __shfl_xor(s, 4, 64);
        s += __shfl_xor(s, 8, 64);
        int gp = base + row;
        if (r == 0 && gp < P) out[gp] = s + b2v;
    }
}

extern "C" void kernel_launch(void* const* d_in, const int* in_sizes, int n_in,
                              void* d_out, int out_size, void* d_ws, size_t ws_size,
                              hipStream_t stream) {
    const float* x  = (const float*)d_in[0];
    const int*   eI = (const int*)d_in[1];
    const int*   eD = (const int*)d_in[2];
    const int*   eL = (const int*)d_in[3];
    const float* Wconv = (const float*)d_in[4];
    const float* bconv = (const float*)d_in[5];
    const float* W1 = (const float*)d_in[6];
    const float* b1 = (const float*)d_in[7];
    const float* W2 = (const float*)d_in[8];
    const float* b2 = (const float*)d_in[9];

    int N = in_sizes[0] / 256;
    int E = in_sizes[1] / 2;
    int P = in_sizes[3] / 2;
    long NH = (long)N * 128;
    int n2 = 2 * N;
    int NB = (n2 + 127) >> NBSHIFT;   // coarse buckets (<=1024)

    // ---- workspace layout ----
    float* ws = (float*)d_ws;
    ushort_t* xlb = (ushort_t*)ws;          // N*128 ushort (bf16 xl)
    ushort_t* zh = xlb + NH;                // N*128 ushort (bf16 z)
    float* dI = (float*)(zh + NH);          // N
    float* dD = dI + N;                     // N
    int* iws = (int*)(dD + N);
    int* cnt = iws;                 // 2N
    int* off = cnt + n2;            // 2N
    int* cur = off + n2;            // 2N
    int nb = (n2 + 255) / 256;
    int* partials = cur + n2;       // padded to 64 ints
    int* ccnt = partials + ((nb + 63) & ~63);   // 1024
    int* gcur = ccnt + 1024;                    // 1024
    int2* edg = (int2*)(gcur + 1024);           // 2E int2 (final {src,coef})
    int2* tmp = edg + 2 * (long)E;              // 2E int2 (coarse-sorted {src,dst'})
    ushort_t* w1f = (ushort_t*)(tmp + 2 * (long)E);  // 3*16384
    ushort_t* btch = w1f + 3 * 16384;                // 32768
    ushort_t* btcl = btch + 32768;                   // 32768
    float* out = (float*)d_out;

    // weight preps
    prep_bt_conv<<<128, 256, 0, stream>>>(Wconv, btch, btcl);
    prep_w1frag<<<192, 256, 0, stream>>>(W1, w1f);

    // xl = bf16(x @ W_conv)
    dim3 gx((N + 127) / 128, 1);
    gemm_mfma_hilo_bf16<<<gx, 256, 0, stream>>>(x, btch, btcl, xlb, N, 256, 128);

    // CSR build: fine degree counts + offsets
    zero_ints<<<(n2 + 255) / 256, 256, 0, stream>>>(cnt, n2);
    zero_ints<<<4, 256, 0, stream>>>(ccnt, 1024);
    count_deg<<<(E + 255) / 256, 256, 0, stream>>>(eI + E, eD + E, cnt, N, E);
    scan_partial<<<nb, 256, 0, stream>>>(cnt, partials, n2);
    scan_partials_excl2<<<1, 512, 0, stream>>>(partials, nb);
    scan_final<<<nb, 256, 0, stream>>>(cnt, partials, off, cur, dI, dD, N, n2);

    // two-level edge sort: block-aggregated coarse scatter, then fine scatter
    coarse_count<<<256, 256, 0, stream>>>(eI + E, eD + E, ccnt, N, E, NB);
    coarse_scan<<<1, 1024, 0, stream>>>(ccnt, gcur, NB);
    coarse_scatter2<<<256, 256, 0, stream>>>(eI, eI + E, eD, eD + E, gcur, tmp, N, E, NB);
    fine_scatter<<<1024, 256, 0, stream>>>(tmp, cur, dI, dD, edg, N, 2 * E);

    // gather + combine -> bf16 z
    gather_combine3<<<(N + 3) / 4, 256, 0, stream>>>(xlb, off, edg, dI, dD,
                                                     bconv, zh, N, 2 * E);

    // decode (8-wave, 64KB ping-pong W staging — measured-best 95us)
    decode_mfma7<<<(P + 127) / 128, 512, 0, stream>>>(zh, eL, eL + P, w1f,
                                                      b1, W2, b2, out, P);
}